// Round 9
// baseline (1495.639 us; speedup 1.0000x reference)
//
#include <hip/hip_runtime.h>

#define EE 131072
#define NNODE 16384
#define FEAT 120
#define NS 512
#define NB 256
#define KCAT 1344

typedef unsigned short u16;
typedef __bf16 bf16x8 __attribute__((ext_vector_type(8)));
typedef float f32x4 __attribute__((ext_vector_type(4)));
typedef unsigned short ushort8 __attribute__((ext_vector_type(8)));
typedef unsigned short us4 __attribute__((ext_vector_type(4)));

__device__ __forceinline__ float b2f(u16 u) {
  union { unsigned int i; float f; } x; x.i = ((unsigned int)u) << 16; return x.f;
}
__device__ __forceinline__ u16 f2b(float f) {
  union { float f; unsigned int i; } x; x.f = f;
  unsigned int lsb = (x.i >> 16) & 1u;
  x.i += 0x7fffu + lsb;
  return (u16)(x.i >> 16);
}
__device__ __forceinline__ u16 f2b_fast(float f) {
  __bf16 h = (__bf16)f;
  union { __bf16 h; u16 u; } x; x.h = h; return x.u;
}
__device__ __forceinline__ float rdany(const void* p, long i, int f32) {
  return f32 ? ((const float*)p)[i] : b2f(((const u16*)p)[i]);
}

__device__ __forceinline__ void gload16(const u16* g, u16* l) {
  __builtin_amdgcn_global_load_lds(
      (__attribute__((address_space(1))) void*)(u16*)g,
      (__attribute__((address_space(3))) void*)l, 16, 0, 0);
}

// ---------------- fused prep: detect + 19 converts + outf zero (1 launch) ----------------
struct PrepArgs {
  long cum[20];
  const void* src[19];
  u16* dst[19];
  float* outf;
  int* flag;
  const u16* nodes;
};

__global__ __launch_bounds__(256) void megaprep(PrepArgs a) {
  __shared__ int scnt[4];
  {
    u16 v = a.nodes[threadIdx.x];
    int e = (v >> 7) & 0xFF;
    unsigned long long b = __ballot(e >= 0x48);
    if ((threadIdx.x & 63) == 0) scnt[threadIdx.x >> 6] = __popcll(b);
  }
  __syncthreads();
  const int f32 = (scnt[0] + scnt[1] + scnt[2] + scnt[3]) >= 16;
  if (blockIdx.x == 0 && threadIdx.x == 0) *a.flag = f32;

  long i = (long)blockIdx.x * 256 + threadIdx.x;
  const long total = a.cum[19];
  if (i < total) {
    int s = 0;
    while (i >= a.cum[s + 1]) s++;
    long local = i - a.cum[s];
    a.dst[s][local] = f32 ? f2b(((const float*)a.src[s])[local])
                          : ((const u16*)a.src[s])[local];
  } else {
    long j = i - total;
    if (j < EE) a.outf[j] = 0.f;
  }
}

// ---------------- fused weight prep: 4 transposes + build_wcat (1 launch) ----------------
struct WprepArgs {
  const u16* tin[4];
  u16* tout[4];
  const u16 *W0, *W1, *W2;
  u16* wcT;
};

__device__ __forceinline__ void do_transpose(const u16* in, u16* out, int R, int C, int rem) {
  __shared__ u16 tile[32][33];
  const int bx = C >> 5;
  const int c0 = (rem % bx) * 32, r0 = (rem / bx) * 32;
  const int tx = threadIdx.x & 31, ty = threadIdx.x >> 5;
  for (int i = 0; i < 32; i += 8) {
    int r = r0 + ty + i, c = c0 + tx;
    if (r < R && c < C) tile[ty + i][tx] = in[(long)r * C + c];
  }
  __syncthreads();
  for (int i = 0; i < 32; i += 8) {
    int r = r0 + tx, c = c0 + ty + i;
    if (r < R && c < C) out[(long)c * R + r] = tile[tx][ty + i];
  }
}

__global__ __launch_bounds__(256) void wprep(WprepArgs a) {
  int b = blockIdx.x;
  if (b < 256) { do_transpose(a.tin[0], a.tout[0], 256, 1024, b); return; }
  b -= 256;
  if (b < 512) { do_transpose(a.tin[1], a.tout[1], 1024, 512, b); return; }
  b -= 512;
  if (b < 512) { do_transpose(a.tin[2], a.tout[2], 512, 1024, b); return; }
  b -= 512;
  if (b < 1024) { do_transpose(a.tin[3], a.tout[3], 1024, 1024, b); return; }
  b -= 1024;
  int idx = b * 256 + threadIdx.x;
  if (idx >= NS * KCAT) return;
  int w = idx / KCAT, k = idx - w * KCAT;
  const float fan = 36.66060556f;  // sqrt(1344)
  float val;
  if (k < 1024) {
    int u = k >> 5, v = k & 31;
    val = 0.5f * (b2f(a.W0[(u * 32 + v) * NS + w]) + b2f(a.W0[(v * 32 + u) * NS + w])) / fan;
  } else if (k < 1280) {
    int j = k - 1024;
    int u = j >> 4, v = j & 15;
    val = 0.5f * (b2f(a.W1[(u * 16 + v) * NS + w]) + b2f(a.W1[(v * 16 + u) * NS + w])) /
          (fan * 1.7320508076f);
  } else {
    int j = k - 1280;
    int u = j >> 3, v = j & 7;
    val = 0.5f * (b2f(a.W2[(u * 8 + v) * NS + w]) + b2f(a.W2[(v * 8 + u) * NS + w])) /
          (fan * 2.2360679775f);
  }
  a.wcT[idx] = f2b(val);
}

// ---------------- per-edge geometry + embedding + outer products ----------------
// Vectorized stores: emb 4/lane (us4), L0 16/lane (2x ushort8),
// L1 4/lane (us4), L2 1/lane scalar.
__global__ __launch_bounds__(256) void edge_prep(
    const u16* __restrict__ nodes, const void* __restrict__ pos, const void* __restrict__ cell,
    const void* __restrict__ shift, const int* __restrict__ eidx, const int* __restrict__ batch,
    u16* __restrict__ emb, u16* __restrict__ ocat, int e0, const int* __restrict__ flag) {
  const int wave = threadIdx.x >> 6, lane = threadIdx.x & 63;
  const int el = blockIdx.x * 4 + wave;
  const int e = e0 + el;
  const int f32 = *flag;
  __shared__ u16 sxs[4][FEAT], sxd[4][FEAT];
  const int src = eidx[e], dst = eidx[EE + e];
  for (int i = lane; i < FEAT; i += 64) {
    sxs[wave][i] = nodes[(long)src * FEAT + i];
    sxd[wave][i] = nodes[(long)dst * FEAT + i];
  }
  __syncthreads();
  const int b = batch[src];
  float s0 = rdany(shift, (long)e * 3, f32), s1 = rdany(shift, (long)e * 3 + 1, f32),
        s2 = rdany(shift, (long)e * 3 + 2, f32);
  float d2 = 0.f;
#pragma unroll
  for (int j = 0; j < 3; j++) {
    float tv = s0 * rdany(cell, b * 9 + j, f32) + s1 * rdany(cell, b * 9 + 3 + j, f32) +
               s2 * rdany(cell, b * 9 + 6 + j, f32);
    float rv = rdany(pos, dst * 3 + j, f32) - rdany(pos, src * 3 + j, f32) + tv;
    d2 += rv * rv;
  }
  float dist = sqrtf(d2);
  float r = 1.0f / (dist + 1e-6f);
  const float c0 = 0.5345224838f;   // sqrt(2/7)
  const float pi7 = 0.44879895051f; // pi/7
  {
    us4 ev;
#pragma unroll
    for (int j = 0; j < 4; j++) {
      int n = lane * 4 + j;
      ev[j] = f2b(c0 * sinf((float)(n + 1) * pi7 * r) / r);
    }
    *(us4*)&emb[(long)el * NB + lane * 4] = ev;
  }
  const u16* xs = sxs[wave];
  const u16* xd = sxd[wave];
  u16* orow = ocat + (long)el * KCAT;
  // L0: k = lane*16 + j (j 0..15): u = lane>>1, v = (lane&1)*16 + j
  {
    const float xu = b2f(xs[lane >> 1]);
    const int v0 = (lane & 1) * 16;
    const ushort8 xd0 = *(const ushort8*)&xd[v0];
    const ushort8 xd1 = *(const ushort8*)&xd[v0 + 8];
    ushort8 o0, o1;
#pragma unroll
    for (int j = 0; j < 8; j++) {
      o0[j] = f2b(xu * b2f(xd0[j]));
      o1[j] = f2b(xu * b2f(xd1[j]));
    }
    *(ushort8*)&orow[lane * 16] = o0;
    *(ushort8*)&orow[lane * 16 + 8] = o1;
  }
  // L1: k = lane*4 + j (j 0..3): u = lane>>2, v = (lane&3)*4 + j
  {
    const int u = lane >> 2;
    us4 o;
#pragma unroll
    for (int j = 0; j < 4; j++) {
      const int v = (lane & 3) * 4 + j;
      float s = 0.f;
#pragma unroll
      for (int i = 0; i < 3; i++) s += b2f(xs[32 + u * 3 + i]) * b2f(xd[32 + v * 3 + i]);
      o[j] = f2b(s);
    }
    *(us4*)&orow[1024 + lane * 4] = o;
  }
  // L2: 1/lane
  {
    int u = lane >> 3, v = lane & 7;
    float s = 0.f;
#pragma unroll
    for (int i = 0; i < 5; i++) s += b2f(xs[80 + u * 5 + i]) * b2f(xd[80 + v * 5 + i]);
    orow[1280 + lane] = f2b(s);
  }
}

// ---------------- 128x128-tile MFMA GEMM, 2 blocks/CU ----------------
// C(MxN) = act(A(MxK) @ BT(NxK)^T + bias)
// 256 threads = 4 waves (2M x 2N, wave tile 64x64); 16x16x32 MFMA; BK=64.
// LDS 64 KiB (2 ops x 2 dbuf x 16 KiB) -> 2 blocks/CU: inter-block overlap
// covers the __syncthreads vmcnt/lgkm drains (m97/m114 mechanism).
// Plain loop: stage(t+1) at top; read 16 frags; 32 MFMA; one __syncthreads.
// Zero-conflict swizzle (rows are 64 cols = 128 B = 8 segs, same as before):
//   LDS[row][seg] = G[row][seg ^ (row&7)]; source pre-swizzled
//   (gseg = (tid&7) ^ ((tid>>3)&7)); read side XORs ((row_l&7)<<4).
#define STGA(buf, kk)                                                      \
  do {                                                                     \
    _Pragma("unroll") for (int i = 0; i < 4; i++)                          \
        gload16(Ag + (i * 32) * (long)K + (kk), &lA[buf][i * 2048 + tid * 8]); \
  } while (0)
#define STGB(buf, kk)                                                      \
  do {                                                                     \
    _Pragma("unroll") for (int i = 0; i < 4; i++)                          \
        gload16(Bg + (i * 32) * (long)K + (kk), &lB[buf][i * 2048 + tid * 8]); \
  } while (0)
#define RDA(buf, fm, ks)                                                   \
  (*(const bf16x8*)((const char*)&lA[buf][0] +                             \
                    ((wm * 64 + (fm)*16 + row_l) * 128 + ((ks) ? ir1 : ir0))))
#define RDB(buf, fn, ks)                                                   \
  (*(const bf16x8*)((const char*)&lB[buf][0] +                             \
                    ((wn * 64 + (fn)*16 + row_l) * 128 + ((ks) ? ir1 : ir0))))
#define MF16(a, b, c) __builtin_amdgcn_mfma_f32_16x16x32_bf16(a, b, c, 0, 0, 0)

template <int ACT, int OF32, int HEAD>
__global__ __launch_bounds__(256, 2) void gemm_bt(const u16* __restrict__ A,
                                                  const u16* __restrict__ BT,
                                                  const u16* __restrict__ bias,
                                                  void* __restrict__ Cv,
                                                  const u16* __restrict__ hw,
                                                  float* __restrict__ outf, int N, int K) {
  __shared__ __align__(16) u16 lA[2][8192];
  __shared__ __align__(16) u16 lB[2][8192];
  const int tid = threadIdx.x;
  const int lane = tid & 63;
  const int wave = tid >> 6;
  const int wm = wave >> 1, wn = wave & 1;  // 2 x 2 wave grid
  const int row_l = lane & 15;
  const int kq16 = (lane >> 4) << 4;
  const int swz = (row_l & 7) << 4;
  const int ir0 = kq16 ^ swz;          // in-row byte offset, ks=0
  const int ir1 = (64 + kq16) ^ swz;   // in-row byte offset, ks=1

  const int nbn = N >> 7;
  int idx = blockIdx.x;
  if ((gridDim.x & 7) == 0) {  // XCD-aware swizzle (bijective: grid % 8 == 0)
    int per = gridDim.x >> 3;
    idx = (blockIdx.x & 7) * per + (blockIdx.x >> 3);
  }
  const int mi = idx / nbn;
  const int ni = idx - mi * nbn;
  const long m0 = (long)mi * 128;
  const int n0 = ni << 7;
  const int nk = K >> 6;

  // staging: thread stages rows {tid>>3 + 32i}, pre-swizzled 16B seg
  const int srow = tid >> 3;
  const int gseg = (tid & 7) ^ (srow & 7);
  const u16* Ag = A + (m0 + srow) * (long)K + gseg * 8;
  const u16* Bg = BT + (long)(n0 + srow) * K + gseg * 8;

  f32x4 acc[4][4];
#pragma unroll
  for (int i = 0; i < 4; i++)
#pragma unroll
    for (int j = 0; j < 4; j++)
#pragma unroll
      for (int q = 0; q < 4; q++) acc[i][j][q] = 0.f;

  // prologue: stage tile0, drain, barrier
  STGA(0, 0);
  STGB(0, 0);
  asm volatile("s_waitcnt vmcnt(0)" ::: "memory");
  __builtin_amdgcn_s_barrier();

  bf16x8 af[4][2], bf[4][2];

  for (int t = 0; t < nk; ++t) {
    const int cur = t & 1, nxt = cur ^ 1;
    if (t + 1 < nk) {
      STGA(nxt, (t + 1) * 64);
      STGB(nxt, (t + 1) * 64);
    }
#pragma unroll
    for (int f = 0; f < 4; f++) { af[f][0] = RDA(cur, f, 0); af[f][1] = RDA(cur, f, 1); }
#pragma unroll
    for (int g = 0; g < 4; g++) { bf[g][0] = RDB(cur, g, 0); bf[g][1] = RDB(cur, g, 1); }
#pragma unroll
    for (int f = 0; f < 4; f++)
#pragma unroll
      for (int g = 0; g < 4; g++)
#pragma unroll
        for (int ks = 0; ks < 2; ks++)
          acc[f][g] = MF16(af[f][ks], bf[g][ks], acc[f][g]);
    __syncthreads();  // drains vmcnt (stage t+1 landed) + lgkm; all waves done reading cur
  }

  // ---- epilogue (16x16x32 C layout: col = lane&15, row = (lane>>4)*4 + reg) ----
  const int rql = (lane >> 4) * 2;
  const int cl = lane & 15;
  float* Cf = (float*)Cv;
  u16* Cb = (u16*)Cv;
  if (HEAD) {
    float bv[4], hv[4];
#pragma unroll
    for (int g = 0; g < 4; g++) {
      const int col = n0 + wn * 64 + g * 16 + cl;
      bv[g] = b2f(bias[col]);
      hv[g] = b2f(hw[col]);
    }
#pragma unroll
    for (int fm = 0; fm < 4; fm++) {
#pragma unroll
      for (int q = 0; q < 4; q++) {
        float s = 0.f;
#pragma unroll
        for (int g = 0; g < 4; g++) {
          float v = acc[fm][g][q] + bv[g];
          if (ACT) v = __fdividef(v, 1.0f + __expf(-v));
          s += v * hv[g];
        }
        s += __shfl_xor(s, 1);
        s += __shfl_xor(s, 2);
        s += __shfl_xor(s, 4);
        s += __shfl_xor(s, 8);
        if (cl == 0) {
          long row = m0 + wm * 64 + fm * 16 + rql * 2 + q;
          atomicAdd(&outf[row], s);
        }
      }
    }
  } else {
#pragma unroll
    for (int fm = 0; fm < 4; fm++) {
#pragma unroll
      for (int g = 0; g < 4; g++) {
        const int col = n0 + wn * 64 + g * 16 + cl;
        const float bvv = bias ? b2f(bias[col]) : 0.0f;
#pragma unroll
        for (int q = 0; q < 4; q++) {
          long row = m0 + wm * 64 + fm * 16 + rql * 2 + q;
          float v = acc[fm][g][q] + bvv;
          if (ACT) v = __fdividef(v, 1.0f + __expf(-v));
          if (OF32)
            Cf[row * N + col] = v;
          else
            Cb[row * N + col] = f2b_fast(v);
        }
      }
    }
  }
}

// ---------------- LayerNorm * distfilter (in-place over distfilter) ----------------
__global__ __launch_bounds__(256) void ln_mul_k(const float* __restrict__ mixed,
                                                const u16* __restrict__ g,
                                                const u16* __restrict__ bvec,
                                                u16* __restrict__ dfreg) {
  const int wave = threadIdx.x >> 6, lane = threadIdx.x & 63;
  const long e = (long)blockIdx.x * 4 + wave;
  const float* row = mixed + e * NS;
  float x[8];
  f32x4 v0 = *(const f32x4*)&row[lane * 8];
  f32x4 v1 = *(const f32x4*)&row[lane * 8 + 4];
#pragma unroll
  for (int j = 0; j < 4; j++) { x[j] = v0[j]; x[4 + j] = v1[j]; }
  float s = 0.f, sq = 0.f;
#pragma unroll
  for (int j = 0; j < 8; j++) { s += x[j]; sq += x[j] * x[j]; }
  for (int o = 32; o; o >>= 1) { s += __shfl_xor(s, o); sq += __shfl_xor(sq, o); }
  float mu = s * (1.0f / 512.0f);
  float var = sq * (1.0f / 512.0f) - mu * mu;
  float rstd = rsqrtf(var + 1e-5f);
  u16* drow = dfreg + e * NS;
  ushort8 dv = *(const ushort8*)&drow[lane * 8];
  ushort8 ov;
#pragma unroll
  for (int j = 0; j < 8; j++) {
    int c = lane * 8 + j;
    float val = (x[j] - mu) * rstd * b2f(g[c]) + b2f(bvec[c]);
    ov[j] = f2b(val * b2f(dv[j]));
  }
  *(ushort8*)&drow[lane * 8] = ov;
}

// ---------------- final head: bias + dtype convert ----------------
__global__ __launch_bounds__(256) void head_finish(const float* __restrict__ outf,
                                                   const u16* __restrict__ b,
                                                   void* __restrict__ out,
                                                   const int* __restrict__ flag) {
  int e = blockIdx.x * 256 + threadIdx.x;
  float v = outf[e] + b2f(b[0]);
  if (*flag)
    ((float*)out)[e] = v;
  else
    ((u16*)out)[e] = f2b(v);
}

extern "C" void kernel_launch(void* const* d_in, const int* in_sizes, int n_in, void* d_out,
                              int out_size, void* d_ws, size_t ws_size, hipStream_t stream) {
  const int* eidx = (const int*)d_in[19];
  const int* batch = (const int*)d_in[20];

  char* ws = (char*)d_ws;
  size_t off = 0;
  auto alloc = [&](size_t bytes) {
    char* p = ws + off;
    off += (bytes + 255) & ~(size_t)255;
    return p;
  };

  int* flag = (int*)alloc(256);
  float* outf = (float*)alloc((size_t)EE * 4);

  // normalize all 19 float tensors to bf16 copies — single fused launch
  PrepArgs pa;
  u16* cv[19];
  long cum = 0;
  for (int i = 0; i < 19; i++) {
    long n = in_sizes[i];
    cv[i] = (u16*)alloc((size_t)n * 2);
    pa.cum[i] = cum;
    pa.src[i] = d_in[i];
    pa.dst[i] = cv[i];
    cum += n;
  }
  pa.cum[19] = cum;
  pa.outf = outf;
  pa.flag = flag;
  pa.nodes = (const u16*)d_in[0];
  {
    long tot = cum + EE;
    megaprep<<<(int)((tot + 255) / 256), 256, 0, stream>>>(pa);
  }
  const u16* nodes = cv[0];
  const u16* ln_g = cv[7];
  const u16* ln_b = cv[8];
  const u16* df_b1 = cv[10];
  const u16* df_b2 = cv[12];
  const u16* mi_b1 = cv[14];
  const u16* mi_b2 = cv[16];
  const u16* mo_w = cv[17];
  const u16* mo_b = cv[18];

  u16* w1T = (u16*)alloc(1024 * 256 * 2);
  u16* w2T = (u16*)alloc(512 * 1024 * 2);
  u16* m1T = (u16*)alloc(1024 * 512 * 2);
  u16* m2T = (u16*)alloc((size_t)1024 * 1024 * 2);
  u16* wcT = (u16*)alloc((size_t)NS * KCAT * 2);

  // weight prep — single fused launch (4 transposes + wcat = 4992 blocks)
  WprepArgs wa;
  wa.tin[0] = cv[9];  wa.tout[0] = w1T;   // df_w1 256x1024
  wa.tin[1] = cv[11]; wa.tout[1] = w2T;   // df_w2 1024x512
  wa.tin[2] = cv[13]; wa.tout[2] = m1T;   // mi_w1 512x1024
  wa.tin[3] = cv[15]; wa.tout[3] = m2T;   // mi_w2 1024x1024
  wa.W0 = cv[4]; wa.W1 = cv[5]; wa.W2 = cv[6];
  wa.wcT = wcT;
  wprep<<<4992, 256, 0, stream>>>(wa);

  // per-edge bytes: ocat 2688 + emb 512 + h1/mixed 2048 + dfb 1024 = 6272
  int nchunk = 1;
  while (nchunk < 64) {
    size_t CHs = (size_t)(EE / nchunk);
    size_t need = off + CHs * 6272 + 8192;
    if (need <= ws_size) break;
    nchunk <<= 1;
  }
  const int CH = EE / nchunk;

  u16* ocat = (u16*)alloc((size_t)CH * KCAT * 2);  // reused as h2
  u16* emb = (u16*)alloc((size_t)CH * NB * 2);
  u16* h1 = (u16*)alloc((size_t)CH * 1024 * 2);  // reused as mixed(f32)
  u16* dfb = (u16*)alloc((size_t)CH * NS * 2);   // distfilter, then reg in-place
  u16* h2 = ocat;
  float* mixed = (float*)h1;

  const int RB = CH / 128;  // m-row blocks per chunk (128-row tiles)
  for (int c = 0; c < nchunk; c++) {
    const int eb = c * CH;
    edge_prep<<<CH / 4, 256, 0, stream>>>(nodes, d_in[1], d_in[2], d_in[3], eidx, batch, emb,
                                          ocat, eb, flag);

    // distance-filter MLP
    gemm_bt<1, 0, 0><<<RB * 8, 256, 0, stream>>>(emb, w1T, df_b1, h1, nullptr, nullptr, 1024, 256);
    gemm_bt<0, 0, 0><<<RB * 4, 256, 0, stream>>>(h1, w2T, df_b2, dfb, nullptr, nullptr, 512, 1024);

    // tensor-product mixing -> mixed (fp32)
    gemm_bt<0, 1, 0><<<RB * 4, 256, 0, stream>>>(ocat, wcT, nullptr, mixed, nullptr, nullptr, 512,
                                                 1344);

    // LayerNorm * distfilter -> reg (in-place over dfb)
    ln_mul_k<<<CH / 4, 256, 0, stream>>>(mixed, ln_g, ln_b, dfb);

    // output MLP; last GEMM fuses the head dot-product
    gemm_bt<1, 0, 0><<<RB * 8, 256, 0, stream>>>(dfb, m1T, mi_b1, h2, nullptr, nullptr, 1024, 512);
    gemm_bt<1, 0, 1><<<RB * 8, 256, 0, stream>>>(h2, m2T, mi_b2, nullptr, mo_w, outf + eb, 1024,
                                                 1024);
  }
  head_finish<<<EE / 256, 256, 0, stream>>>(outf, mo_b, d_out, flag);
}

// Round 10
// 1324.649 us; speedup vs baseline: 1.1291x; 1.1291x over previous
//
#include <hip/hip_runtime.h>

#define EE 131072
#define NNODE 16384
#define FEAT 120
#define NS 512
#define NB 256
#define KCAT 1344

typedef unsigned short u16;
typedef __bf16 bf16x8 __attribute__((ext_vector_type(8)));
typedef float f32x4 __attribute__((ext_vector_type(4)));
typedef unsigned short ushort8 __attribute__((ext_vector_type(8)));
typedef unsigned short us4 __attribute__((ext_vector_type(4)));

__device__ __forceinline__ float b2f(u16 u) {
  union { unsigned int i; float f; } x; x.i = ((unsigned int)u) << 16; return x.f;
}
__device__ __forceinline__ u16 f2b(float f) {
  union { float f; unsigned int i; } x; x.f = f;
  unsigned int lsb = (x.i >> 16) & 1u;
  x.i += 0x7fffu + lsb;
  return (u16)(x.i >> 16);
}
__device__ __forceinline__ u16 f2b_fast(float f) {
  __bf16 h = (__bf16)f;
  union { __bf16 h; u16 u; } x; x.h = h; return x.u;
}
__device__ __forceinline__ float rdany(const void* p, long i, int f32) {
  return f32 ? ((const float*)p)[i] : b2f(((const u16*)p)[i]);
}

__device__ __forceinline__ void gload16(const u16* g, u16* l) {
  __builtin_amdgcn_global_load_lds(
      (__attribute__((address_space(1))) void*)(u16*)g,
      (__attribute__((address_space(3))) void*)l, 16, 0, 0);
}

// ---------------- fused prep: detect + 19 converts + outf zero (1 launch) ----------------
struct PrepArgs {
  long cum[20];
  const void* src[19];
  u16* dst[19];
  float* outf;
  int* flag;
  const u16* nodes;
};

__global__ __launch_bounds__(256) void megaprep(PrepArgs a) {
  __shared__ int scnt[4];
  {
    u16 v = a.nodes[threadIdx.x];
    int e = (v >> 7) & 0xFF;
    unsigned long long b = __ballot(e >= 0x48);
    if ((threadIdx.x & 63) == 0) scnt[threadIdx.x >> 6] = __popcll(b);
  }
  __syncthreads();
  const int f32 = (scnt[0] + scnt[1] + scnt[2] + scnt[3]) >= 16;
  if (blockIdx.x == 0 && threadIdx.x == 0) *a.flag = f32;

  long i = (long)blockIdx.x * 256 + threadIdx.x;
  const long total = a.cum[19];
  if (i < total) {
    int s = 0;
    while (i >= a.cum[s + 1]) s++;
    long local = i - a.cum[s];
    a.dst[s][local] = f32 ? f2b(((const float*)a.src[s])[local])
                          : ((const u16*)a.src[s])[local];
  } else {
    long j = i - total;
    if (j < EE) a.outf[j] = 0.f;
  }
}

// ---------------- fused weight prep: 4 transposes + build_wcat (1 launch) ----------------
struct WprepArgs {
  const u16* tin[4];
  u16* tout[4];
  const u16 *W0, *W1, *W2;
  u16* wcT;
};

__device__ __forceinline__ void do_transpose(const u16* in, u16* out, int R, int C, int rem) {
  __shared__ u16 tile[32][33];
  const int bx = C >> 5;
  const int c0 = (rem % bx) * 32, r0 = (rem / bx) * 32;
  const int tx = threadIdx.x & 31, ty = threadIdx.x >> 5;
  for (int i = 0; i < 32; i += 8) {
    int r = r0 + ty + i, c = c0 + tx;
    if (r < R && c < C) tile[ty + i][tx] = in[(long)r * C + c];
  }
  __syncthreads();
  for (int i = 0; i < 32; i += 8) {
    int r = r0 + tx, c = c0 + ty + i;
    if (r < R && c < C) out[(long)c * R + r] = tile[tx][ty + i];
  }
}

__global__ __launch_bounds__(256) void wprep(WprepArgs a) {
  int b = blockIdx.x;
  if (b < 256) { do_transpose(a.tin[0], a.tout[0], 256, 1024, b); return; }
  b -= 256;
  if (b < 512) { do_transpose(a.tin[1], a.tout[1], 1024, 512, b); return; }
  b -= 512;
  if (b < 512) { do_transpose(a.tin[2], a.tout[2], 512, 1024, b); return; }
  b -= 512;
  if (b < 1024) { do_transpose(a.tin[3], a.tout[3], 1024, 1024, b); return; }
  b -= 1024;
  int idx = b * 256 + threadIdx.x;
  if (idx >= NS * KCAT) return;
  int w = idx / KCAT, k = idx - w * KCAT;
  const float fan = 36.66060556f;  // sqrt(1344)
  float val;
  if (k < 1024) {
    int u = k >> 5, v = k & 31;
    val = 0.5f * (b2f(a.W0[(u * 32 + v) * NS + w]) + b2f(a.W0[(v * 32 + u) * NS + w])) / fan;
  } else if (k < 1280) {
    int j = k - 1024;
    int u = j >> 4, v = j & 15;
    val = 0.5f * (b2f(a.W1[(u * 16 + v) * NS + w]) + b2f(a.W1[(v * 16 + u) * NS + w])) /
          (fan * 1.7320508076f);
  } else {
    int j = k - 1280;
    int u = j >> 3, v = j & 7;
    val = 0.5f * (b2f(a.W2[(u * 8 + v) * NS + w]) + b2f(a.W2[(v * 8 + u) * NS + w])) /
          (fan * 2.2360679775f);
  }
  a.wcT[idx] = f2b(val);
}

// ---------------- per-edge geometry + embedding + outer products ----------------
// Vectorized stores: emb 4/lane (us4), L0 16/lane (2x ushort8),
// L1 4/lane (us4), L2 1/lane scalar.
__global__ __launch_bounds__(256) void edge_prep(
    const u16* __restrict__ nodes, const void* __restrict__ pos, const void* __restrict__ cell,
    const void* __restrict__ shift, const int* __restrict__ eidx, const int* __restrict__ batch,
    u16* __restrict__ emb, u16* __restrict__ ocat, int e0, const int* __restrict__ flag) {
  const int wave = threadIdx.x >> 6, lane = threadIdx.x & 63;
  const int el = blockIdx.x * 4 + wave;
  const int e = e0 + el;
  const int f32 = *flag;
  __shared__ u16 sxs[4][FEAT], sxd[4][FEAT];
  const int src = eidx[e], dst = eidx[EE + e];
  for (int i = lane; i < FEAT; i += 64) {
    sxs[wave][i] = nodes[(long)src * FEAT + i];
    sxd[wave][i] = nodes[(long)dst * FEAT + i];
  }
  __syncthreads();
  const int b = batch[src];
  float s0 = rdany(shift, (long)e * 3, f32), s1 = rdany(shift, (long)e * 3 + 1, f32),
        s2 = rdany(shift, (long)e * 3 + 2, f32);
  float d2 = 0.f;
#pragma unroll
  for (int j = 0; j < 3; j++) {
    float tv = s0 * rdany(cell, b * 9 + j, f32) + s1 * rdany(cell, b * 9 + 3 + j, f32) +
               s2 * rdany(cell, b * 9 + 6 + j, f32);
    float rv = rdany(pos, dst * 3 + j, f32) - rdany(pos, src * 3 + j, f32) + tv;
    d2 += rv * rv;
  }
  float dist = sqrtf(d2);
  float r = 1.0f / (dist + 1e-6f);
  const float c0 = 0.5345224838f;   // sqrt(2/7)
  const float pi7 = 0.44879895051f; // pi/7
  {
    us4 ev;
#pragma unroll
    for (int j = 0; j < 4; j++) {
      int n = lane * 4 + j;
      ev[j] = f2b(c0 * sinf((float)(n + 1) * pi7 * r) / r);
    }
    *(us4*)&emb[(long)el * NB + lane * 4] = ev;
  }
  const u16* xs = sxs[wave];
  const u16* xd = sxd[wave];
  u16* orow = ocat + (long)el * KCAT;
  // L0: k = lane*16 + j (j 0..15): u = lane>>1, v = (lane&1)*16 + j
  {
    const float xu = b2f(xs[lane >> 1]);
    const int v0 = (lane & 1) * 16;
    const ushort8 xd0 = *(const ushort8*)&xd[v0];
    const ushort8 xd1 = *(const ushort8*)&xd[v0 + 8];
    ushort8 o0, o1;
#pragma unroll
    for (int j = 0; j < 8; j++) {
      o0[j] = f2b(xu * b2f(xd0[j]));
      o1[j] = f2b(xu * b2f(xd1[j]));
    }
    *(ushort8*)&orow[lane * 16] = o0;
    *(ushort8*)&orow[lane * 16 + 8] = o1;
  }
  // L1: k = lane*4 + j (j 0..3): u = lane>>2, v = (lane&3)*4 + j
  {
    const int u = lane >> 2;
    us4 o;
#pragma unroll
    for (int j = 0; j < 4; j++) {
      const int v = (lane & 3) * 4 + j;
      float s = 0.f;
#pragma unroll
      for (int i = 0; i < 3; i++) s += b2f(xs[32 + u * 3 + i]) * b2f(xd[32 + v * 3 + i]);
      o[j] = f2b(s);
    }
    *(us4*)&orow[1024 + lane * 4] = o;
  }
  // L2: 1/lane
  {
    int u = lane >> 3, v = lane & 7;
    float s = 0.f;
#pragma unroll
    for (int i = 0; i < 5; i++) s += b2f(xs[80 + u * 5 + i]) * b2f(xd[80 + v * 5 + i]);
    orow[1280 + lane] = f2b(s);
  }
}

// ---------------- 256x256-tile lookahead-pipelined MFMA GEMM (round-7, best) ----------------
// 512 threads = 8 waves (2M x 4N, wave tile 128x64); 16x16x32 MFMA; BK=64.
// One-phase-lookahead reads; counted lgkm waits (no blunt lgkmcnt(0));
// 2 barriers/tile; vmcnt(0) at ph3 drains only tile t+1's landed batch.
// Zero-conflict LDS swizzle: LDS[row][seg] = G[row][seg ^ (row&7)],
// source pre-swizzled, dest linear, read side XORs ((row_l&7)<<4).
#define STGA(buf, h, part, kk)                                             \
  gload16(Ag + ((h)*128 + (part)*64) * (long)K + (kk),                      \
          &lA[buf][(h)*8192 + (part)*4096 + tid * 8])
#define STGB(buf, h, part, kk)                                             \
  gload16(Bg + ((h)*128 + (part)*64) * (long)K + (kk),                      \
          &lB[buf][(h)*8192 + (part)*4096 + tid * 8])
#define RDA(buf, fm, ks)                                                   \
  (*(const bf16x8*)((const char*)&lA[buf][0] +                             \
                    ((wm * 128 + (fm)*16 + row_l) * 128 + ((ks) ? ir1 : ir0))))
#define RDB(buf, fn, ks)                                                   \
  (*(const bf16x8*)((const char*)&lB[buf][0] +                             \
                    ((wn * 64 + (fn)*16 + row_l) * 128 + ((ks) ? ir1 : ir0))))
#define MF16(a, b, c) __builtin_amdgcn_mfma_f32_16x16x32_bf16(a, b, c, 0, 0, 0)
#define MFQn(mh, nh, Af, Bf)                                               \
  do {                                                                     \
    _Pragma("unroll") for (int f = 0; f < 4; f++)                          \
        _Pragma("unroll") for (int g = 0; g < 2; g++)                      \
            _Pragma("unroll") for (int ks = 0; ks < 2; ks++)               \
                acc[(mh)*4 + f][(nh)*2 + g] =                              \
        MF16(Af[f][ks], Bf[g][ks], acc[(mh)*4 + f][(nh)*2 + g]);           \
  } while (0)

template <int ACT, int OF32, int HEAD>
__global__ __launch_bounds__(512, 2) void gemm_bt(const u16* __restrict__ A,
                                                  const u16* __restrict__ BT,
                                                  const u16* __restrict__ bias,
                                                  void* __restrict__ Cv,
                                                  const u16* __restrict__ hw,
                                                  float* __restrict__ outf, int N, int K) {
  __shared__ __align__(16) u16 lA[2][16384];
  __shared__ __align__(16) u16 lB[2][16384];
  const int tid = threadIdx.x;
  const int lane = tid & 63;
  const int wave = tid >> 6;
  const int wm = wave >> 2, wn = wave & 3;  // 2 x 4 wave grid
  const int row_l = lane & 15;
  const int kq16 = (lane >> 4) << 4;
  const int swz = (row_l & 7) << 4;
  const int ir0 = kq16 ^ swz;          // in-row byte offset, ks=0
  const int ir1 = (64 + kq16) ^ swz;   // in-row byte offset, ks=1

  const int nbn = N >> 8;
  int idx = blockIdx.x;
  if ((gridDim.x & 7) == 0) {  // XCD-aware swizzle (bijective: grid % 8 == 0)
    int per = gridDim.x >> 3;
    idx = (blockIdx.x & 7) * per + (blockIdx.x >> 3);
  }
  const int mi = idx / nbn;
  const int ni = idx - mi * nbn;
  const long m0 = (long)mi * 256;
  const int n0 = ni << 8;
  const int nk = K >> 6;

  // staging: thread stages row (tid>>3) of each 64-row part, pre-swizzled 16B seg
  const int srow = tid >> 3;
  const int gseg = (tid & 7) ^ (srow & 7);
  const u16* Ag = A + (m0 + srow) * (long)K + gseg * 8;
  const u16* Bg = BT + (long)(n0 + srow) * K + gseg * 8;

  f32x4 acc[8][4];
#pragma unroll
  for (int i = 0; i < 8; i++)
#pragma unroll
    for (int j = 0; j < 4; j++)
#pragma unroll
      for (int q = 0; q < 4; q++) acc[i][j][q] = 0.f;

  // prologue: full tile0 (8 loads) + full tile1 (8 loads); wait tile0 only
  STGA(0, 0, 0, 0); STGA(0, 0, 1, 0); STGA(0, 1, 0, 0); STGA(0, 1, 1, 0);
  STGB(0, 0, 0, 0); STGB(0, 0, 1, 0); STGB(0, 1, 0, 0); STGB(0, 1, 1, 0);
  if (nk > 1) {
    STGA(1, 0, 0, 64); STGA(1, 0, 1, 64); STGA(1, 1, 0, 64); STGA(1, 1, 1, 64);
    STGB(1, 0, 0, 64); STGB(1, 0, 1, 64); STGB(1, 1, 0, 64); STGB(1, 1, 1, 64);
    asm volatile("s_waitcnt vmcnt(8)" ::: "memory");
  } else {
    asm volatile("s_waitcnt vmcnt(0)" ::: "memory");
  }
  __builtin_amdgcn_s_barrier();

  bf16x8 af0[4][2], af1[4][2], b01[2][2], b23[2][2];

  // pre-loop: Q1(t0) operand reads
#pragma unroll
  for (int f = 0; f < 4; f++) { af0[f][0] = RDA(0, f, 0); af0[f][1] = RDA(0, f, 1); }
#pragma unroll
  for (int g = 0; g < 2; g++) { b01[g][0] = RDB(0, g, 0); b01[g][1] = RDB(0, g, 1); }

  for (int t = 0; t < nk; ++t) {
    const int cur = t & 1, nxt = cur ^ 1;
    const int kN2 = (t + 2) << 6;
    const bool p1 = (t + 1) < nk;
    const bool p2 = (t + 2) < nk;

    // ---- ph1: issue b23(t) reads; MFMA Q1 = af0*b01 ----
#pragma unroll
    for (int g = 0; g < 2; g++) { b23[g][0] = RDB(cur, 2 + g, 0); b23[g][1] = RDB(cur, 2 + g, 1); }
    __builtin_amdgcn_sched_barrier(0);
    __builtin_amdgcn_s_setprio(1);
    MFQn(0, 0, af0, b01);
    __builtin_amdgcn_s_setprio(0);

    // ---- ph2: issue af1(t) reads; MFMA Q2 = af0*b23 ----
#pragma unroll
    for (int f = 0; f < 4; f++) { af1[f][0] = RDA(cur, 4 + f, 0); af1[f][1] = RDA(cur, 4 + f, 1); }
    __builtin_amdgcn_sched_barrier(0);
    __builtin_amdgcn_s_setprio(1);
    MFQn(0, 1, af0, b23);
    __builtin_amdgcn_s_setprio(0);

    // ---- ph3: vmcnt(0) drains t+1's batch (t+2 not yet issued); barrier;
    //          lookahead af0(t+1); stage B(t+2)h0; MFMA Q3 = af1*b01 ----
    asm volatile("s_waitcnt vmcnt(0)" ::: "memory");
    __builtin_amdgcn_s_barrier();
    if (p1) {
#pragma unroll
      for (int f = 0; f < 4; f++) { af0[f][0] = RDA(nxt, f, 0); af0[f][1] = RDA(nxt, f, 1); }
    }
    if (p2) { STGB(cur, 0, 0, kN2); STGB(cur, 0, 1, kN2); }
    __builtin_amdgcn_sched_barrier(0);
    __builtin_amdgcn_s_setprio(1);
    MFQn(1, 0, af1, b01);
    __builtin_amdgcn_s_setprio(0);

    // ---- ph4: barrier; stage rest of t+2; MFMA Q4 = af1*b23; read b01(t+1) ----
    __builtin_amdgcn_s_barrier();
    if (p2) {
      STGB(cur, 1, 0, kN2); STGB(cur, 1, 1, kN2);
      STGA(cur, 0, 0, kN2); STGA(cur, 0, 1, kN2);
      STGA(cur, 1, 0, kN2); STGA(cur, 1, 1, kN2);
    }
    __builtin_amdgcn_sched_barrier(0);
    __builtin_amdgcn_s_setprio(1);
    MFQn(1, 1, af1, b23);
    __builtin_amdgcn_s_setprio(0);
    if (p1) {
#pragma unroll
      for (int g = 0; g < 2; g++) { b01[g][0] = RDB(nxt, g, 0); b01[g][1] = RDB(nxt, g, 1); }
      __builtin_amdgcn_sched_barrier(0);
    }
  }

  // ---- epilogue (16x16x32 C layout: col = lane&15, row = (lane>>4)*4 + reg) ----
  const int rql = (lane >> 4) * 2;
  const int cl = lane & 15;
  float* Cf = (float*)Cv;
  u16* Cb = (u16*)Cv;
  if (HEAD) {
    float bv[4], hv[4];
#pragma unroll
    for (int g = 0; g < 4; g++) {
      const int col = n0 + wn * 64 + g * 16 + cl;
      bv[g] = b2f(bias[col]);
      hv[g] = b2f(hw[col]);
    }
#pragma unroll
    for (int fm = 0; fm < 8; fm++) {
#pragma unroll
      for (int q = 0; q < 4; q++) {
        float s = 0.f;
#pragma unroll
        for (int g = 0; g < 4; g++) {
          float v = acc[fm][g][q] + bv[g];
          if (ACT) v = __fdividef(v, 1.0f + __expf(-v));
          s += v * hv[g];
        }
        s += __shfl_xor(s, 1);
        s += __shfl_xor(s, 2);
        s += __shfl_xor(s, 4);
        s += __shfl_xor(s, 8);
        if (cl == 0) {
          long row = m0 + wm * 128 + fm * 16 + rql * 2 + q;
          atomicAdd(&outf[row], s);
        }
      }
    }
  } else {
#pragma unroll
    for (int fm = 0; fm < 8; fm++) {
#pragma unroll
      for (int g = 0; g < 4; g++) {
        const int col = n0 + wn * 64 + g * 16 + cl;
        const float bvv = bias ? b2f(bias[col]) : 0.0f;
#pragma unroll
        for (int q = 0; q < 4; q++) {
          long row = m0 + wm * 128 + fm * 16 + rql * 2 + q;
          float v = acc[fm][g][q] + bvv;
          if (ACT) v = __fdividef(v, 1.0f + __expf(-v));
          if (OF32)
            Cf[row * N + col] = v;
          else
            Cb[row * N + col] = f2b_fast(v);
        }
      }
    }
  }
}

// ---------------- LayerNorm * distfilter (in-place over distfilter) ----------------
__global__ __launch_bounds__(256) void ln_mul_k(const float* __restrict__ mixed,
                                                const u16* __restrict__ g,
                                                const u16* __restrict__ bvec,
                                                u16* __restrict__ dfreg) {
  const int wave = threadIdx.x >> 6, lane = threadIdx.x & 63;
  const long e = (long)blockIdx.x * 4 + wave;
  const float* row = mixed + e * NS;
  float x[8];
  f32x4 v0 = *(const f32x4*)&row[lane * 8];
  f32x4 v1 = *(const f32x4*)&row[lane * 8 + 4];
#pragma unroll
  for (int j = 0; j < 4; j++) { x[j] = v0[j]; x[4 + j] = v1[j]; }
  float s = 0.f, sq = 0.f;
#pragma unroll
  for (int j = 0; j < 8; j++) { s += x[j]; sq += x[j] * x[j]; }
  for (int o = 32; o; o >>= 1) { s += __shfl_xor(s, o); sq += __shfl_xor(sq, o); }
  float mu = s * (1.0f / 512.0f);
  float var = sq * (1.0f / 512.0f) - mu * mu;
  float rstd = rsqrtf(var + 1e-5f);
  u16* drow = dfreg + e * NS;
  ushort8 dv = *(const ushort8*)&drow[lane * 8];
  ushort8 ov;
#pragma unroll
  for (int j = 0; j < 8; j++) {
    int c = lane * 8 + j;
    float val = (x[j] - mu) * rstd * b2f(g[c]) + b2f(bvec[c]);
    ov[j] = f2b(val * b2f(dv[j]));
  }
  *(ushort8*)&drow[lane * 8] = ov;
}

// ---------------- final head: bias + dtype convert ----------------
__global__ __launch_bounds__(256) void head_finish(const float* __restrict__ outf,
                                                   const u16* __restrict__ b,
                                                   void* __restrict__ out,
                                                   const int* __restrict__ flag) {
  int e = blockIdx.x * 256 + threadIdx.x;
  float v = outf[e] + b2f(b[0]);
  if (*flag)
    ((float*)out)[e] = v;
  else
    ((u16*)out)[e] = f2b(v);
}

extern "C" void kernel_launch(void* const* d_in, const int* in_sizes, int n_in, void* d_out,
                              int out_size, void* d_ws, size_t ws_size, hipStream_t stream) {
  const int* eidx = (const int*)d_in[19];
  const int* batch = (const int*)d_in[20];

  char* ws = (char*)d_ws;
  size_t off = 0;
  auto alloc = [&](size_t bytes) {
    char* p = ws + off;
    off += (bytes + 255) & ~(size_t)255;
    return p;
  };

  int* flag = (int*)alloc(256);
  float* outf = (float*)alloc((size_t)EE * 4);

  // normalize all 19 float tensors to bf16 copies — single fused launch
  PrepArgs pa;
  u16* cv[19];
  long cum = 0;
  for (int i = 0; i < 19; i++) {
    long n = in_sizes[i];
    cv[i] = (u16*)alloc((size_t)n * 2);
    pa.cum[i] = cum;
    pa.src[i] = d_in[i];
    pa.dst[i] = cv[i];
    cum += n;
  }
  pa.cum[19] = cum;
  pa.outf = outf;
  pa.flag = flag;
  pa.nodes = (const u16*)d_in[0];
  {
    long tot = cum + EE;
    megaprep<<<(int)((tot + 255) / 256), 256, 0, stream>>>(pa);
  }
  const u16* nodes = cv[0];
  const u16* ln_g = cv[7];
  const u16* ln_b = cv[8];
  const u16* df_b1 = cv[10];
  const u16* df_b2 = cv[12];
  const u16* mi_b1 = cv[14];
  const u16* mi_b2 = cv[16];
  const u16* mo_w = cv[17];
  const u16* mo_b = cv[18];

  u16* w1T = (u16*)alloc(1024 * 256 * 2);
  u16* w2T = (u16*)alloc(512 * 1024 * 2);
  u16* m1T = (u16*)alloc(1024 * 512 * 2);
  u16* m2T = (u16*)alloc((size_t)1024 * 1024 * 2);
  u16* wcT = (u16*)alloc((size_t)NS * KCAT * 2);

  // weight prep — single fused launch (4 transposes + wcat = 4992 blocks)
  WprepArgs wa;
  wa.tin[0] = cv[9];  wa.tout[0] = w1T;   // df_w1 256x1024
  wa.tin[1] = cv[11]; wa.tout[1] = w2T;   // df_w2 1024x512
  wa.tin[2] = cv[13]; wa.tout[2] = m1T;   // mi_w1 512x1024
  wa.tin[3] = cv[15]; wa.tout[3] = m2T;   // mi_w2 1024x1024
  wa.W0 = cv[4]; wa.W1 = cv[5]; wa.W2 = cv[6];
  wa.wcT = wcT;
  wprep<<<4992, 256, 0, stream>>>(wa);

  // per-edge bytes: ocat 2688 + emb 512 + h1/mixed 2048 + dfb 1024 = 6272
  int nchunk = 1;
  while (nchunk < 64) {
    size_t CHs = (size_t)(EE / nchunk);
    size_t need = off + CHs * 6272 + 8192;
    if (need <= ws_size) break;
    nchunk <<= 1;
  }
  const int CH = EE / nchunk;

  u16* ocat = (u16*)alloc((size_t)CH * KCAT * 2);  // reused as h2
  u16* emb = (u16*)alloc((size_t)CH * NB * 2);
  u16* h1 = (u16*)alloc((size_t)CH * 1024 * 2);  // reused as mixed(f32)
  u16* dfb = (u16*)alloc((size_t)CH * NS * 2);   // distfilter, then reg in-place
  u16* h2 = ocat;
  float* mixed = (float*)h1;

  const int RB = CH / 256;  // m-row blocks per chunk (256-row tiles)
  for (int c = 0; c < nchunk; c++) {
    const int eb = c * CH;
    edge_prep<<<CH / 4, 256, 0, stream>>>(nodes, d_in[1], d_in[2], d_in[3], eidx, batch, emb,
                                          ocat, eb, flag);

    // distance-filter MLP
    gemm_bt<1, 0, 0><<<RB * 4, 512, 0, stream>>>(emb, w1T, df_b1, h1, nullptr, nullptr, 1024, 256);
    gemm_bt<0, 0, 0><<<RB * 2, 512, 0, stream>>>(h1, w2T, df_b2, dfb, nullptr, nullptr, 512, 1024);

    // tensor-product mixing -> mixed (fp32)
    gemm_bt<0, 1, 0><<<RB * 2, 512, 0, stream>>>(ocat, wcT, nullptr, mixed, nullptr, nullptr, 512,
                                                 1344);

    // LayerNorm * distfilter -> reg (in-place over dfb)
    ln_mul_k<<<CH / 4, 256, 0, stream>>>(mixed, ln_g, ln_b, dfb);

    // output MLP; last GEMM fuses the head dot-product
    gemm_bt<1, 0, 0><<<RB * 4, 512, 0, stream>>>(dfb, m1T, mi_b1, h2, nullptr, nullptr, 1024, 512);
    gemm_bt<1, 0, 1><<<RB * 4, 512, 0, stream>>>(h2, m2T, mi_b2, nullptr, mo_w, outf + eb, 1024,
                                                 1024);
  }
  head_finish<<<EE / 256, 256, 0, stream>>>(outf, mo_b, d_out, flag);
}